// Round 1
// baseline (194.927 us; speedup 1.0000x reference)
//
#include <hip/hip_runtime.h>
#include <math.h>

// Problem constants
#define NA   12            // atoms per residue
#define NL   256           // residues
#define NN   3072          // NL*NA atoms per batch
#define NB   2             // batches
#define ED   32            // embedding dim
#define KNB  30            // neighbours
#define BIGD 1000000.0f

// Flat output offsets (all stored as float32; int outputs stored as float values)
#define OFF_COORDS 0                       // 2*3072*3   = 18432
#define OFF_MASK   18432                   // 2*3072     = 6144
#define OFF_ENC    24576                   // 2*3072*32  = 196608
#define OFF_DIST   221184                  // 2*3072*30  = 184320
#define OFF_IDX    405504                  // 2*3072*30  = 184320
// total 589824

// ---------------------------------------------------------------------------
// Kernel 1: per-batch mask sum + analytic graph-norm stats (mean, 1/std per c)
// ws layout: ws[b*64 + c] = mean, ws[b*64 + 32 + c] = rstd
// ---------------------------------------------------------------------------
__global__ __launch_bounds__(64) void stats_kernel(const int* __restrict__ mask,
                                                   const float* __restrict__ emb,
                                                   float* __restrict__ ws) {
    int lane = threadIdx.x;
    float s0 = 0.f, s1 = 0.f;
    for (int l = lane; l < NL; l += 64) {
        s0 += (float)mask[l];
        s1 += (float)mask[NL + l];
    }
#pragma unroll
    for (int m = 1; m < 64; m <<= 1) {
        s0 += __shfl_xor(s0, m);
        s1 += __shfl_xor(s1, m);
    }
    if (lane < ED) {
        int c = lane;
        float e[NA];
        float colsum = 0.f;
#pragma unroll
        for (int a = 0; a < NA; ++a) { e[a] = emb[a * ED + c]; colsum += e[a]; }
#pragma unroll
        for (int b = 0; b < NB; ++b) {
            float S   = (b == 0) ? s0 : s1;
            float cnt = fmaxf(12.0f * S, 1.0f);
            float mean = S * colsum / cnt;
            float acc = 0.f;
#pragma unroll
            for (int a = 0; a < NA; ++a) { float d = e[a] - mean; acc += d * d; }
            float var  = (S * acc + ((float)NN - 12.0f * S) * mean * mean) / cnt;
            float rstd = 1.0f / sqrtf(var + 1e-5f);
            ws[b * 64 + c]      = mean;
            ws[b * 64 + 32 + c] = rstd;
        }
    }
}

// ---------------------------------------------------------------------------
// Kernel 2: encode elementwise + atom_coords copy + atom_mask expand
// grid covers 196608 threads
// ---------------------------------------------------------------------------
__global__ __launch_bounds__(256) void encode_kernel(const float* __restrict__ coords,
                                                     const int* __restrict__ mask,
                                                     const float* __restrict__ emb,
                                                     const float* __restrict__ scale,
                                                     const float* __restrict__ shift,
                                                     const float* __restrict__ ws,
                                                     float* __restrict__ out) {
    int idx = blockIdx.x * blockDim.x + threadIdx.x;
    if (idx < NB * NN * ED) {
        int c = idx & (ED - 1);
        int n = (idx >> 5) % NN;
        int b = idx / (NN * ED);
        int mi = mask[b * NL + n / NA];
        float v = 0.f;
        if (mi) {
            float mean = ws[b * 64 + c];
            float rstd = ws[b * 64 + 32 + c];
            v = (emb[(n % NA) * ED + c] - mean) * rstd * scale[c] + shift[c];
        }
        out[OFF_ENC + idx] = v;
    }
    if (idx < NB * NN * 3) {
        out[OFF_COORDS + idx] = coords[idx];   // pure reshape
    }
    if (idx < NB * NN) {
        int b = idx / NN, n = idx % NN;
        out[OFF_MASK + idx] = (float)mask[b * NL + n / NA];
    }
}

// ---------------------------------------------------------------------------
// Kernel 3: per-row top-30 nearest neighbours.
// One wave (64 threads) per query row; 6144 blocks.
// Distances to LDS; 30x wave-argmin with cached per-lane minimum; only the
// winning lane rescans its 48 entries after removal.
// ---------------------------------------------------------------------------
__global__ __launch_bounds__(64) void topk_kernel(const float* __restrict__ coords,
                                                  const int* __restrict__ mask,
                                                  float* __restrict__ out) {
    __shared__ float dist[NN];
    int row  = blockIdx.x;          // 0..6143
    int lane = threadIdx.x;
    int b = row / NN;
    int i = row - b * NN;
    const float* cb = coords + (size_t)b * NN * 3;
    const int*   mb = mask + b * NL;

    int mi = mb[i / NA];
    if (!mi) {                       // padded row: dist=BIG, idx=0
        if (lane < KNB) {
            out[OFF_DIST + (size_t)row * KNB + lane] = BIGD;
            out[OFF_IDX  + (size_t)row * KNB + lane] = 0.f;
        }
        return;
    }

    float qx = cb[i * 3 + 0], qy = cb[i * 3 + 1], qz = cb[i * 3 + 2];

    float mn = 1e30f;
    int   mnidx = 0x7fffffff;
#pragma unroll 4
    for (int t = 0; t < NN / 64; ++t) {
        int j = t * 64 + lane;
        float dx = cb[j * 3 + 0] - qx;
        float dy = cb[j * 3 + 1] - qy;
        float dz = cb[j * 3 + 2] - qz;
        float s  = dx * dx + dy * dy + dz * dz + 1e-6f;
        float d  = mb[j / NA] ? sqrtf(s) : BIGD;
        dist[j] = d;
        if (d < mn) { mn = d; mnidx = j; }   // ascending j => smallest idx kept on ties
    }

    float rv = 0.f;
    int   ri = 0;
    for (int it = 0; it < KNB; ++it) {
        float wv = mn;
        int   wi = mnidx;
#pragma unroll
        for (int m = 1; m < 64; m <<= 1) {
            float ov = __shfl_xor(wv, m);
            int   oi = __shfl_xor(wi, m);
            if (ov < wv || (ov == wv && oi < wi)) { wv = ov; wi = oi; }
        }
        if (lane == it) { rv = wv; ri = wi; }
        if (lane == (wi & 63)) {     // owner lane: remove winner, rebuild cached min
            dist[wi] = 1e30f;
            mn = 1e30f; mnidx = 0x7fffffff;
#pragma unroll 4
            for (int t = 0; t < NN / 64; ++t) {
                int j = t * 64 + lane;
                float d = dist[j];
                if (d < mn) { mn = d; mnidx = j; }
            }
        }
    }

    if (lane < KNB) {
        out[OFF_DIST + (size_t)row * KNB + lane] = rv;
        out[OFF_IDX  + (size_t)row * KNB + lane] = (float)ri;
    }
}

// ---------------------------------------------------------------------------
extern "C" void kernel_launch(void* const* d_in, const int* in_sizes, int n_in,
                              void* d_out, int out_size, void* d_ws, size_t ws_size,
                              hipStream_t stream) {
    const float* coords = (const float*)d_in[0];   // (2,256,12,3)
    const int*   mask   = (const int*)d_in[1];     // (2,256)
    const float* emb    = (const float*)d_in[2];   // (12,32)
    const float* scale  = (const float*)d_in[3];   // (32)
    const float* shift  = (const float*)d_in[4];   // (32)
    float* out = (float*)d_out;
    float* ws  = (float*)d_ws;

    stats_kernel<<<1, 64, 0, stream>>>(mask, emb, ws);
    encode_kernel<<<(NB * NN * ED + 255) / 256, 256, 0, stream>>>(
        coords, mask, emb, scale, shift, ws, out);
    topk_kernel<<<NB * NN, 64, 0, stream>>>(coords, mask, out);
}

// Round 2
// 146.084 us; speedup vs baseline: 1.3343x; 1.3343x over previous
//
#include <hip/hip_runtime.h>
#include <math.h>

// Problem constants
#define NA   12            // atoms per residue
#define NL   256           // residues
#define NN   3072          // NL*NA atoms per batch
#define NB   2             // batches
#define ED   32            // embedding dim
#define KNB  30            // neighbours
#define BIGD 1000000.0f

// Flat output offsets (all stored as float32; int outputs stored as float values)
#define OFF_COORDS 0                       // 2*3072*3   = 18432
#define OFF_MASK   18432                   // 2*3072     = 6144
#define OFF_ENC    24576                   // 2*3072*32  = 196608
#define OFF_DIST   221184                  // 2*3072*30  = 184320
#define OFF_IDX    405504                  // 2*3072*30  = 184320
// total 589824

// ws layout: [0..127] floats = stats (mean/rstd per batch); byte 512+: packed float4 coords
#define WS_C4_BYTE_OFF 512
#define WS_NEEDED (WS_C4_BYTE_OFF + (size_t)NB * NN * 16)

// ---------------------------------------------------------------------------
// Kernel 1: per-batch mask sum + analytic graph-norm stats (mean, 1/std per c)
// ---------------------------------------------------------------------------
__global__ __launch_bounds__(64) void stats_kernel(const int* __restrict__ mask,
                                                   const float* __restrict__ emb,
                                                   float* __restrict__ ws) {
    int lane = threadIdx.x;
    float s0 = 0.f, s1 = 0.f;
    for (int l = lane; l < NL; l += 64) {
        s0 += (float)mask[l];
        s1 += (float)mask[NL + l];
    }
#pragma unroll
    for (int m = 1; m < 64; m <<= 1) {
        s0 += __shfl_xor(s0, m);
        s1 += __shfl_xor(s1, m);
    }
    if (lane < ED) {
        int c = lane;
        float e[NA];
        float colsum = 0.f;
#pragma unroll
        for (int a = 0; a < NA; ++a) { e[a] = emb[a * ED + c]; colsum += e[a]; }
#pragma unroll
        for (int b = 0; b < NB; ++b) {
            float S   = (b == 0) ? s0 : s1;
            float cnt = fmaxf(12.0f * S, 1.0f);
            float mean = S * colsum / cnt;
            float acc = 0.f;
#pragma unroll
            for (int a = 0; a < NA; ++a) { float d = e[a] - mean; acc += d * d; }
            float var  = (S * acc + ((float)NN - 12.0f * S) * mean * mean) / cnt;
            float rstd = 1.0f / sqrtf(var + 1e-5f);
            ws[b * 64 + c]      = mean;
            ws[b * 64 + 32 + c] = rstd;
        }
    }
}

// ---------------------------------------------------------------------------
// Kernel 2: encode elementwise + atom_coords copy + atom_mask expand +
//           packed float4 {x,y,z,valid} for topk
// ---------------------------------------------------------------------------
__global__ __launch_bounds__(256) void encode_kernel(const float* __restrict__ coords,
                                                     const int* __restrict__ mask,
                                                     const float* __restrict__ emb,
                                                     const float* __restrict__ scale,
                                                     const float* __restrict__ shift,
                                                     const float* __restrict__ ws,
                                                     float* __restrict__ out,
                                                     float4* __restrict__ c4pack) {
    int idx = blockIdx.x * blockDim.x + threadIdx.x;
    if (idx < NB * NN * ED) {
        int c = idx & (ED - 1);
        int n = (idx >> 5) % NN;
        int b = idx / (NN * ED);
        int mi = mask[b * NL + n / NA];
        float v = 0.f;
        if (mi) {
            float mean = ws[b * 64 + c];
            float rstd = ws[b * 64 + 32 + c];
            v = (emb[(n % NA) * ED + c] - mean) * rstd * scale[c] + shift[c];
        }
        out[OFF_ENC + idx] = v;
    }
    if (idx < NB * NN * 3) {
        out[OFF_COORDS + idx] = coords[idx];   // pure reshape
    }
    if (idx < NB * NN) {
        int b = idx / NN, n = idx - b * NN;
        float m = (float)mask[b * NL + n / NA];
        out[OFF_MASK + idx] = m;
        if (c4pack) {
            float4 v;
            v.x = coords[idx * 3 + 0];
            v.y = coords[idx * 3 + 1];
            v.z = coords[idx * 3 + 2];
            v.w = m;
            c4pack[idx] = v;
        }
    }
}

// ---------------------------------------------------------------------------
// Kernel 3: per-row top-30. One wave per row. Distances in 48 VGPRs/lane;
// 6 cached group-minima; scalar-branched 8-element rescan per extraction.
// ---------------------------------------------------------------------------
#define RESCAN(G)                                                              \
    {                                                                          \
        float m_ = 1e30f; int mj_ = 0x7fffffff;                                \
        _Pragma("unroll")                                                      \
        for (int u = 0; u < 8; ++u) {                                          \
            const int t = (G) * 8 + u;                                         \
            bool valid = (((xm >> t) & 1ull) == 0ull);                         \
            float dv = valid ? d[t] : 1e30f;                                   \
            if (dv < m_) { m_ = dv; mj_ = t * 64 + lane; }                     \
        }                                                                      \
        gmn[(G)] = m_; gmj[(G)] = mj_;                                         \
    }

template <bool PACKED>
__global__ __launch_bounds__(64) void topk_kernel(const float4* __restrict__ c4,
                                                  const float* __restrict__ coords,
                                                  const int* __restrict__ mask,
                                                  float* __restrict__ out) {
    int row  = blockIdx.x;          // 0..6143
    int lane = threadIdx.x;
    int b = (row >= NN) ? 1 : 0;
    int i = row - b * NN;

    // own row validity + query coords
    float qx, qy, qz, qw;
    if (PACKED) {
        float4 q4 = c4[b * NN + i];
        qx = q4.x; qy = q4.y; qz = q4.z; qw = q4.w;
    } else {
        const float* cb = coords + (size_t)b * NN * 3;
        qx = cb[i * 3 + 0]; qy = cb[i * 3 + 1]; qz = cb[i * 3 + 2];
        qw = (float)mask[b * NL + i / NA];
    }
    if (qw == 0.f) {                 // padded row: dist=BIG, idx=0
        if (lane < KNB) {
            out[OFF_DIST + (size_t)row * KNB + lane] = BIGD;
            out[OFF_IDX  + (size_t)row * KNB + lane] = 0.f;
        }
        return;
    }

    float d[48];
    float gmn[6];
    int   gmj[6];
#pragma unroll
    for (int g = 0; g < 6; ++g) { gmn[g] = 1e30f; gmj[g] = 0x7fffffff; }

#pragma unroll
    for (int t = 0; t < 48; ++t) {
        int j = t * 64 + lane;
        float x, y, z, w;
        if (PACKED) {
            float4 v = c4[b * NN + j];
            x = v.x; y = v.y; z = v.z; w = v.w;
        } else {
            const float* cb = coords + (size_t)b * NN * 3;
            int r = (j * 43691) >> 19;          // j / 12 (magic)
            w = (float)mask[b * NL + r];
            x = cb[j * 3 + 0]; y = cb[j * 3 + 1]; z = cb[j * 3 + 2];
        }
        float dx = x - qx, dy = y - qy, dz = z - qz;
        float s = dx * dx + dy * dy + dz * dz + 1e-6f;
        float dv = (w != 0.f) ? sqrtf(s) : BIGD;
        d[t] = dv;
        const int g = t >> 3;
        if (dv < gmn[g]) { gmn[g] = dv; gmj[g] = j; }  // ascending j => ties keep smaller idx
    }

    unsigned long long xm = 0ull;   // extracted-slot bitmask (48 bits used)
    float mn = gmn[0]; int mnj = gmj[0];
#pragma unroll
    for (int g = 1; g < 6; ++g) if (gmn[g] < mn) { mn = gmn[g]; mnj = gmj[g]; }

    float rv = BIGD; int ri = 0;
    for (int it = 0; it < KNB; ++it) {
        // wave-wide lexicographic argmin over cached lane minima
        float wv = mn; int wi = mnj;
#pragma unroll
        for (int m = 1; m < 64; m <<= 1) {
            float ov = __shfl_xor(wv, m);
            int   oi = __shfl_xor(wi, m);
            bool take = (ov < wv) || (ov == wv && oi < wi);
            wv = take ? ov : wv;
            wi = take ? oi : wi;
        }
        // winner is wave-uniform: hoist to SGPRs for scalar branching
        wi = __builtin_amdgcn_readfirstlane(wi);
        wv = __int_as_float(__builtin_amdgcn_readfirstlane(__float_as_int(wv)));
        if (lane == it) { rv = wv; ri = wi; }

        int wt    = wi >> 6;        // slot 0..47 (scalar)
        int wlane = wi & 63;        // owner lane (scalar)
        int wg    = wt >> 3;        // group 0..5 (scalar)
        if (lane == wlane) xm |= (1ull << wt);
        switch (wg) {               // scalar branch: rescan only winner's group
            case 0: RESCAN(0); break;
            case 1: RESCAN(1); break;
            case 2: RESCAN(2); break;
            case 3: RESCAN(3); break;
            case 4: RESCAN(4); break;
            default: RESCAN(5); break;
        }
        mn = gmn[0]; mnj = gmj[0];
#pragma unroll
        for (int g = 1; g < 6; ++g) if (gmn[g] < mn) { mn = gmn[g]; mnj = gmj[g]; }
    }

    if (lane < KNB) {
        out[OFF_DIST + (size_t)row * KNB + lane] = rv;
        out[OFF_IDX  + (size_t)row * KNB + lane] = (float)ri;
    }
}

// ---------------------------------------------------------------------------
extern "C" void kernel_launch(void* const* d_in, const int* in_sizes, int n_in,
                              void* d_out, int out_size, void* d_ws, size_t ws_size,
                              hipStream_t stream) {
    const float* coords = (const float*)d_in[0];   // (2,256,12,3)
    const int*   mask   = (const int*)d_in[1];     // (2,256)
    const float* emb    = (const float*)d_in[2];   // (12,32)
    const float* scale  = (const float*)d_in[3];   // (32)
    const float* shift  = (const float*)d_in[4];   // (32)
    float* out = (float*)d_out;
    float* ws  = (float*)d_ws;

    bool packed = (ws_size >= WS_NEEDED);
    float4* c4 = packed ? (float4*)((char*)d_ws + WS_C4_BYTE_OFF) : nullptr;

    stats_kernel<<<1, 64, 0, stream>>>(mask, emb, ws);
    encode_kernel<<<(NB * NN * ED + 255) / 256, 256, 0, stream>>>(
        coords, mask, emb, scale, shift, ws, out, c4);
    if (packed) {
        topk_kernel<true><<<NB * NN, 64, 0, stream>>>(c4, coords, mask, out);
    } else {
        topk_kernel<false><<<NB * NN, 64, 0, stream>>>(nullptr, coords, mask, out);
    }
}

// Round 3
// 138.767 us; speedup vs baseline: 1.4047x; 1.0527x over previous
//
#include <hip/hip_runtime.h>
#include <math.h>

// Problem constants
#define NA   12            // atoms per residue
#define NL   256           // residues
#define NN   3072          // NL*NA atoms per batch
#define NB   2             // batches
#define ED   32            // embedding dim
#define KNB  30            // neighbours
#define BIGD 1000000.0f

// Flat output offsets (all stored as float32; int outputs stored as float values)
#define OFF_COORDS 0                       // 2*3072*3   = 18432
#define OFF_MASK   18432                   // 2*3072     = 6144
#define OFF_ENC    24576                   // 2*3072*32  = 196608
#define OFF_DIST   221184                  // 2*3072*30  = 184320
#define OFF_IDX    405504                  // 2*3072*30  = 184320
// total 589824

// ws layout: [0..127] floats = stats (mean/rstd per batch); byte 512+: packed float4 coords
#define WS_C4_BYTE_OFF 512
#define WS_NEEDED (WS_C4_BYTE_OFF + (size_t)NB * NN * 16)

// ---------------------------------------------------------------------------
// Kernel 1: per-batch mask sum + analytic graph-norm stats (mean, 1/std per c)
// ---------------------------------------------------------------------------
__global__ __launch_bounds__(64) void stats_kernel(const int* __restrict__ mask,
                                                   const float* __restrict__ emb,
                                                   float* __restrict__ ws) {
    int lane = threadIdx.x;
    float s0 = 0.f, s1 = 0.f;
    for (int l = lane; l < NL; l += 64) {
        s0 += (float)mask[l];
        s1 += (float)mask[NL + l];
    }
#pragma unroll
    for (int m = 1; m < 64; m <<= 1) {
        s0 += __shfl_xor(s0, m);
        s1 += __shfl_xor(s1, m);
    }
    if (lane < ED) {
        int c = lane;
        float e[NA];
        float colsum = 0.f;
#pragma unroll
        for (int a = 0; a < NA; ++a) { e[a] = emb[a * ED + c]; colsum += e[a]; }
#pragma unroll
        for (int b = 0; b < NB; ++b) {
            float S   = (b == 0) ? s0 : s1;
            float cnt = fmaxf(12.0f * S, 1.0f);
            float mean = S * colsum / cnt;
            float acc = 0.f;
#pragma unroll
            for (int a = 0; a < NA; ++a) { float dd = e[a] - mean; acc += dd * dd; }
            float var  = (S * acc + ((float)NN - 12.0f * S) * mean * mean) / cnt;
            float rstd = 1.0f / sqrtf(var + 1e-5f);
            ws[b * 64 + c]      = mean;
            ws[b * 64 + 32 + c] = rstd;
        }
    }
}

// ---------------------------------------------------------------------------
// Kernel 2: encode elementwise + atom_coords copy + atom_mask expand +
//           packed float4 {x,y,z,valid} for topk
// ---------------------------------------------------------------------------
__global__ __launch_bounds__(256) void encode_kernel(const float* __restrict__ coords,
                                                     const int* __restrict__ mask,
                                                     const float* __restrict__ emb,
                                                     const float* __restrict__ scale,
                                                     const float* __restrict__ shift,
                                                     const float* __restrict__ ws,
                                                     float* __restrict__ out,
                                                     float4* __restrict__ c4pack) {
    int idx = blockIdx.x * blockDim.x + threadIdx.x;
    if (idx < NB * NN * ED) {
        int c = idx & (ED - 1);
        int n = (idx >> 5) % NN;
        int b = idx / (NN * ED);
        int mi = mask[b * NL + n / NA];
        float v = 0.f;
        if (mi) {
            float mean = ws[b * 64 + c];
            float rstd = ws[b * 64 + 32 + c];
            v = (emb[(n % NA) * ED + c] - mean) * rstd * scale[c] + shift[c];
        }
        out[OFF_ENC + idx] = v;
    }
    if (idx < NB * NN * 3) {
        out[OFF_COORDS + idx] = coords[idx];   // pure reshape
    }
    if (idx < NB * NN) {
        int b = idx / NN, n = idx - b * NN;
        float m = (float)mask[b * NL + n / NA];
        out[OFF_MASK + idx] = m;
        if (c4pack) {
            float4 v;
            v.x = coords[idx * 3 + 0];
            v.y = coords[idx * 3 + 1];
            v.z = coords[idx * 3 + 2];
            v.w = m;
            c4pack[idx] = v;
        }
    }
}

// ---------------------------------------------------------------------------
// Kernel 3: per-row top-30. One wave per row (4 rows per 256-thread block).
// Distances in 48 VGPRs/lane; 6 cached group-minima; scalar-branched
// 8-element rescan per extraction; DPP-ladder lexicographic wave argmin.
// ---------------------------------------------------------------------------

// One DPP step of the lexicographic (value,idx) min ladder.
// update_dpp(old=current, src=current): lanes with invalid DPP source keep old
// (self), making the min a no-op there. All values positive -> float cmp ok.
#define DPP_ARGMIN_STEP(CTRL)                                                  \
    {                                                                          \
        int tv_ = __builtin_amdgcn_update_dpp(vb_, vb_, (CTRL), 0xf, 0xf, false); \
        int ti_ = __builtin_amdgcn_update_dpp(ib_, ib_, (CTRL), 0xf, 0xf, false); \
        float fv_ = __int_as_float(tv_);                                       \
        bool tk_ = (fv_ < mv_) || (fv_ == mv_ && ti_ < mi_);                   \
        mv_ = tk_ ? fv_ : mv_;                                                 \
        mi_ = tk_ ? ti_ : mi_;                                                 \
        vb_ = __float_as_int(mv_); ib_ = mi_;                                  \
    }

#define RESCAN(G, XMH, BASE)                                                   \
    {                                                                          \
        float m_ = 1e30f; int mj_ = 0x7fffffff;                                \
        _Pragma("unroll")                                                      \
        for (int u = 0; u < 8; ++u) {                                          \
            const int t = (G) * 8 + u;                                         \
            bool ext = (((XMH) >> (t - (BASE))) & 1u) != 0u;                   \
            float dv = ext ? 1e30f : d[t];                                     \
            if (dv < m_) { m_ = dv; mj_ = t * 64 + lane; }                     \
        }                                                                      \
        gmn[(G)] = m_; gmj[(G)] = mj_;                                         \
    }

template <bool PACKED>
__global__ __launch_bounds__(256) void topk_kernel(const float4* __restrict__ c4,
                                                   const float* __restrict__ coords,
                                                   const int* __restrict__ mask,
                                                   float* __restrict__ out) {
    int lane = threadIdx.x & 63;
    int row  = blockIdx.x * 4 + (threadIdx.x >> 6);   // 0..6143, one wave per row
    int b = (row >= NN) ? 1 : 0;
    int i = row - b * NN;

    // own row validity + query coords
    float qx, qy, qz, qw;
    if (PACKED) {
        float4 q4 = c4[b * NN + i];
        qx = q4.x; qy = q4.y; qz = q4.z; qw = q4.w;
    } else {
        const float* cb = coords + (size_t)b * NN * 3;
        qx = cb[i * 3 + 0]; qy = cb[i * 3 + 1]; qz = cb[i * 3 + 2];
        qw = (float)mask[b * NL + i / NA];
    }
    if (qw == 0.f) {                 // padded row: dist=BIG, idx=0
        if (lane < KNB) {
            out[OFF_DIST + (size_t)row * KNB + lane] = BIGD;
            out[OFF_IDX  + (size_t)row * KNB + lane] = 0.f;
        }
        return;
    }

    float d[48];
    float gmn[6];
    int   gmj[6];
#pragma unroll
    for (int g = 0; g < 6; ++g) { gmn[g] = 1e30f; gmj[g] = 0x7fffffff; }

#pragma unroll
    for (int t = 0; t < 48; ++t) {
        int j = t * 64 + lane;
        float x, y, z, w;
        if (PACKED) {
            float4 v = c4[b * NN + j];
            x = v.x; y = v.y; z = v.z; w = v.w;
        } else {
            const float* cb = coords + (size_t)b * NN * 3;
            int r = (j * 43691) >> 19;          // j / 12 (magic)
            w = (float)mask[b * NL + r];
            x = cb[j * 3 + 0]; y = cb[j * 3 + 1]; z = cb[j * 3 + 2];
        }
        float dx = x - qx, dy = y - qy, dz = z - qz;
        float s = dx * dx + dy * dy + dz * dz + 1e-6f;
        float dv = (w != 0.f) ? sqrtf(s) : BIGD;
        d[t] = dv;
        const int g = t >> 3;
        if (dv < gmn[g]) { gmn[g] = dv; gmj[g] = j; }  // ascending j => ties keep smaller idx
    }

    unsigned xm_lo = 0u, xm_hi = 0u;   // extracted-slot bitmask (48 bits)
    float mn = gmn[0]; int mnj = gmj[0];
#pragma unroll
    for (int g = 1; g < 6; ++g) if (gmn[g] < mn) { mn = gmn[g]; mnj = gmj[g]; }

    float rv = BIGD; int ri = 0;
    for (int it = 0; it < KNB; ++it) {
        // DPP lexicographic argmin ladder; result lands in lane 63
        float mv_ = mn; int mi_ = mnj;
        int vb_ = __float_as_int(mv_), ib_ = mi_;
        DPP_ARGMIN_STEP(0xB1)   // quad_perm [1,0,3,2]  (xor 1)
        DPP_ARGMIN_STEP(0x4E)   // quad_perm [2,3,0,1]  (xor 2)
        DPP_ARGMIN_STEP(0x141)  // row_half_mirror      (merge quads in octet)
        DPP_ARGMIN_STEP(0x140)  // row_mirror           (merge octets in row16)
        DPP_ARGMIN_STEP(0x142)  // row_bcast15          (row0->row1, row2->row3)
        DPP_ARGMIN_STEP(0x143)  // row_bcast31          (rows01 -> rows23)
        int   wi = __builtin_amdgcn_readlane(ib_, 63);          // SGPR (uniform)
        float wv = __int_as_float(__builtin_amdgcn_readlane(vb_, 63));
        if (lane == it) { rv = wv; ri = wi; }

        int wt    = wi >> 6;            // slot 0..47 (scalar)
        int wlane = wi & 63;            // owner lane (scalar)
        int wg    = wt >> 3;            // group 0..5 (scalar)
        unsigned bit = 1u << (wt & 31); // scalar shift
        switch (wg) {                   // scalar branch: touch only winner's group
            case 0: if (lane == wlane) xm_lo |= bit; RESCAN(0, xm_lo, 0);  break;
            case 1: if (lane == wlane) xm_lo |= bit; RESCAN(1, xm_lo, 0);  break;
            case 2: if (lane == wlane) xm_lo |= bit; RESCAN(2, xm_lo, 0);  break;
            case 3: if (lane == wlane) xm_lo |= bit; RESCAN(3, xm_lo, 0);  break;
            case 4: if (lane == wlane) xm_hi |= bit; RESCAN(4, xm_hi, 32); break;
            default:if (lane == wlane) xm_hi |= bit; RESCAN(5, xm_hi, 32); break;
        }
        mn = gmn[0]; mnj = gmj[0];
#pragma unroll
        for (int g = 1; g < 6; ++g) if (gmn[g] < mn) { mn = gmn[g]; mnj = gmj[g]; }
    }

    if (lane < KNB) {
        out[OFF_DIST + (size_t)row * KNB + lane] = rv;
        out[OFF_IDX  + (size_t)row * KNB + lane] = (float)ri;
    }
}

// ---------------------------------------------------------------------------
extern "C" void kernel_launch(void* const* d_in, const int* in_sizes, int n_in,
                              void* d_out, int out_size, void* d_ws, size_t ws_size,
                              hipStream_t stream) {
    const float* coords = (const float*)d_in[0];   // (2,256,12,3)
    const int*   mask   = (const int*)d_in[1];     // (2,256)
    const float* emb    = (const float*)d_in[2];   // (12,32)
    const float* scale  = (const float*)d_in[3];   // (32)
    const float* shift  = (const float*)d_in[4];   // (32)
    float* out = (float*)d_out;
    float* ws  = (float*)d_ws;

    bool packed = (ws_size >= WS_NEEDED);
    float4* c4 = packed ? (float4*)((char*)d_ws + WS_C4_BYTE_OFF) : nullptr;

    stats_kernel<<<1, 64, 0, stream>>>(mask, emb, ws);
    encode_kernel<<<(NB * NN * ED + 255) / 256, 256, 0, stream>>>(
        coords, mask, emb, scale, shift, ws, out, c4);
    if (packed) {
        topk_kernel<true><<<(NB * NN) / 4, 256, 0, stream>>>(c4, coords, mask, out);
    } else {
        topk_kernel<false><<<(NB * NN) / 4, 256, 0, stream>>>(nullptr, coords, mask, out);
    }
}

// Round 4
// 103.086 us; speedup vs baseline: 1.8909x; 1.3461x over previous
//
#include <hip/hip_runtime.h>
#include <math.h>

// Problem constants
#define NA   12            // atoms per residue
#define NL   256           // residues
#define NN   3072          // NL*NA atoms per batch
#define NB   2             // batches
#define ED   32            // embedding dim
#define KNB  30            // neighbours
#define BIGD 1000000.0f

// Flat output offsets (all stored as float32; int outputs stored as float values)
#define OFF_COORDS 0                       // 2*3072*3   = 18432
#define OFF_MASK   18432                   // 2*3072     = 6144
#define OFF_ENC    24576                   // 2*3072*32  = 196608
#define OFF_DIST   221184                  // 2*3072*30  = 184320
#define OFF_IDX    405504                  // 2*3072*30  = 184320

// ws layout: byte 512+: packed float4 coords {x,y,z,validmask}
#define WS_C4_BYTE_OFF 512
#define WS_NEEDED (WS_C4_BYTE_OFF + (size_t)NB * NN * 16)

// key packing: top 20 bits = float bits of dist (positive -> uint order == float
// order), low 12 bits = atom index (0..3071). min(key) == lexicographic
// (dist, idx) min with smallest-index tie-break == jax top_k semantics.
#define KEYVAL 0xFFFFF000u
#define KEYIDX 0x00000FFFu

static __device__ __forceinline__ unsigned umin32(unsigned a, unsigned b) {
    return a < b ? a : b;
}

// ---------------------------------------------------------------------------
// Kernel 1: fused stats + encode + atom_coords copy + atom_mask expand +
//           packed float4 {x,y,z,valid} for topk.
// Per-wave redundant mask-sum (256 ints) replaces the separate stats kernel.
// ---------------------------------------------------------------------------
__global__ __launch_bounds__(256) void prep_kernel(const float* __restrict__ coords,
                                                   const int* __restrict__ mask,
                                                   const float* __restrict__ emb,
                                                   const float* __restrict__ scale,
                                                   const float* __restrict__ shift,
                                                   float* __restrict__ out,
                                                   float4* __restrict__ c4pack) {
    int idx  = blockIdx.x * 256 + threadIdx.x;     // 0..196607, enc element
    int lane = threadIdx.x & 63;
    int b = idx / (NN * ED);                       // batch (block-uniform)

    // wave-level mask sum for batch b (int4 load: 64 lanes x 4 = 256 residues)
    const int4* m4 = (const int4*)(mask + b * NL);
    int4 mv = m4[lane];
    float S = (float)(mv.x + mv.y + mv.z + mv.w);
#pragma unroll
    for (int m = 1; m < 64; m <<= 1) S += __shfl_xor(S, m);

    // per-channel analytic graph-norm stats
    int c = idx & (ED - 1);
    float e[NA];
    float colsum = 0.f;
#pragma unroll
    for (int a = 0; a < NA; ++a) { e[a] = emb[a * ED + c]; colsum += e[a]; }
    float cnt  = fmaxf(12.0f * S, 1.0f);
    float mean = S * colsum / cnt;
    float acc  = 0.f;
#pragma unroll
    for (int a = 0; a < NA; ++a) { float dd = e[a] - mean; acc += dd * dd; }
    float var  = (S * acc + ((float)NN - 12.0f * S) * mean * mean) / cnt;
    float rstd = 1.0f / sqrtf(var + 1e-5f);

    // encode output
    int n  = (idx >> 5) % NN;
    int mi = mask[b * NL + n / NA];
    float v = 0.f;
    if (mi) {
        float en = emb[(n % NA) * ED + c];         // reload (avoids dynamic reg idx)
        v = (en - mean) * rstd * scale[c] + shift[c];
    }
    out[OFF_ENC + idx] = v;

    if (idx < NB * NN * 3) {
        out[OFF_COORDS + idx] = coords[idx];       // pure reshape
    }
    if (idx < NB * NN) {
        int bb = idx / NN, nn = idx - bb * NN;
        float m = (float)mask[bb * NL + nn / NA];
        out[OFF_MASK + idx] = m;
        if (c4pack) {
            float4 p;
            p.x = coords[idx * 3 + 0];
            p.y = coords[idx * 3 + 1];
            p.z = coords[idx * 3 + 2];
            p.w = m;
            c4pack[idx] = p;
        }
    }
}

// ---------------------------------------------------------------------------
// Kernel 2: per-row top-30. One wave per row (4 rows per 256-thread block).
// 48 packed keys per lane in VGPRs; 6 cached group-min keys; all compares are
// v_min_u32. Scalar-branched 8-element removal+rescan per extraction;
// DPP min ladder for the wave argmin (result in lane 63).
// ---------------------------------------------------------------------------

#define DPP_MIN_STEP(CTRL)                                                        \
    {                                                                             \
        int t_ = __builtin_amdgcn_update_dpp(v_, v_, (CTRL), 0xf, 0xf, false);    \
        v_ = (int)umin32((unsigned)v_, (unsigned)t_);                             \
    }

#define TREE8(A0,A1,A2,A3,A4,A5,A6,A7) \
    umin32(umin32(umin32((A0),(A1)), umin32((A2),(A3))), \
           umin32(umin32((A4),(A5)), umin32((A6),(A7))))

#define REMOVE_RESCAN(G)                                                          \
    {                                                                             \
        _Pragma("unroll")                                                         \
        for (int u = 0; u < 8; ++u) {                                             \
            const int t = (G) * 8 + u;                                            \
            k[t] = (k[t] == wkey) ? 0xFFFFFFFFu : k[t];                           \
        }                                                                         \
        gm[(G)] = TREE8(k[(G)*8+0],k[(G)*8+1],k[(G)*8+2],k[(G)*8+3],              \
                        k[(G)*8+4],k[(G)*8+5],k[(G)*8+6],k[(G)*8+7]);             \
    }

template <bool PACKED>
__global__ __launch_bounds__(256) void topk_kernel(const float4* __restrict__ c4,
                                                   const float* __restrict__ coords,
                                                   const int* __restrict__ mask,
                                                   float* __restrict__ out) {
    int lane = threadIdx.x & 63;
    int row  = blockIdx.x * 4 + (threadIdx.x >> 6);   // 0..6143, one wave per row
    int b = (row >= NN) ? 1 : 0;
    int i = row - b * NN;

    // own row validity + query coords
    float qx, qy, qz, qw;
    if (PACKED) {
        float4 q4 = c4[b * NN + i];
        qx = q4.x; qy = q4.y; qz = q4.z; qw = q4.w;
    } else {
        const float* cb = coords + (size_t)b * NN * 3;
        qx = cb[i * 3 + 0]; qy = cb[i * 3 + 1]; qz = cb[i * 3 + 2];
        qw = (float)mask[b * NL + i / NA];
    }
    if (qw == 0.f) {                 // padded row: dist=BIG, idx=0
        if (lane < KNB) {
            out[OFF_DIST + (size_t)row * KNB + lane] = BIGD;
            out[OFF_IDX  + (size_t)row * KNB + lane] = 0.f;
        }
        return;
    }

    unsigned k[48];
    unsigned gm[6];

#pragma unroll
    for (int t = 0; t < 48; ++t) {
        int j = t * 64 + lane;
        float x, y, z, w;
        if (PACKED) {
            float4 v = c4[b * NN + j];
            x = v.x; y = v.y; z = v.z; w = v.w;
        } else {
            const float* cb = coords + (size_t)b * NN * 3;
            int r = (j * 43691) >> 19;          // j / 12 (magic)
            w = (float)mask[b * NL + r];
            x = cb[j * 3 + 0]; y = cb[j * 3 + 1]; z = cb[j * 3 + 2];
        }
        float dx = x - qx, dy = y - qy, dz = z - qz;
        float s = dx * dx + dy * dy + dz * dz + 1e-6f;
        float dv = (w != 0.f) ? sqrtf(s) : BIGD;
        k[t] = (__float_as_uint(dv) & KEYVAL) | (unsigned)j;
    }
#pragma unroll
    for (int g = 0; g < 6; ++g)
        gm[g] = TREE8(k[g*8+0],k[g*8+1],k[g*8+2],k[g*8+3],
                      k[g*8+4],k[g*8+5],k[g*8+6],k[g*8+7]);

    unsigned cur = umin32(umin32(umin32(gm[0], gm[1]), umin32(gm[2], gm[3])),
                          umin32(gm[4], gm[5]));
    unsigned rkey = 0u;

    for (int it = 0; it < KNB; ++it) {
        // DPP min ladder over cached lane minima; global min lands in lane 63
        int v_ = (int)cur;
        DPP_MIN_STEP(0xB1)   // quad_perm [1,0,3,2]  (xor 1)
        DPP_MIN_STEP(0x4E)   // quad_perm [2,3,0,1]  (xor 2)
        DPP_MIN_STEP(0x141)  // row_half_mirror
        DPP_MIN_STEP(0x140)  // row_mirror
        DPP_MIN_STEP(0x142)  // row_bcast15
        DPP_MIN_STEP(0x143)  // row_bcast31
        unsigned wkey = (unsigned)__builtin_amdgcn_readlane(v_, 63);  // SGPR
        rkey = (lane == it) ? wkey : rkey;

        int wg = (int)((wkey & KEYIDX) >> 9);      // j>>6 = slot, slot>>3 = group
        switch (wg) {                               // scalar branch
            case 0: REMOVE_RESCAN(0); break;
            case 1: REMOVE_RESCAN(1); break;
            case 2: REMOVE_RESCAN(2); break;
            case 3: REMOVE_RESCAN(3); break;
            case 4: REMOVE_RESCAN(4); break;
            default: REMOVE_RESCAN(5); break;
        }
        cur = umin32(umin32(umin32(gm[0], gm[1]), umin32(gm[2], gm[3])),
                     umin32(gm[4], gm[5]));
    }

    if (lane < KNB) {
        out[OFF_DIST + (size_t)row * KNB + lane] = __uint_as_float(rkey & KEYVAL);
        out[OFF_IDX  + (size_t)row * KNB + lane] = (float)(rkey & KEYIDX);
    }
}

// ---------------------------------------------------------------------------
extern "C" void kernel_launch(void* const* d_in, const int* in_sizes, int n_in,
                              void* d_out, int out_size, void* d_ws, size_t ws_size,
                              hipStream_t stream) {
    const float* coords = (const float*)d_in[0];   // (2,256,12,3)
    const int*   mask   = (const int*)d_in[1];     // (2,256)
    const float* emb    = (const float*)d_in[2];   // (12,32)
    const float* scale  = (const float*)d_in[3];   // (32)
    const float* shift  = (const float*)d_in[4];   // (32)
    float* out = (float*)d_out;

    bool packed = (ws_size >= WS_NEEDED);
    float4* c4 = packed ? (float4*)((char*)d_ws + WS_C4_BYTE_OFF) : nullptr;

    prep_kernel<<<(NB * NN * ED) / 256, 256, 0, stream>>>(
        coords, mask, emb, scale, shift, out, c4);
    if (packed) {
        topk_kernel<true><<<(NB * NN) / 4, 256, 0, stream>>>(c4, coords, mask, out);
    } else {
        topk_kernel<false><<<(NB * NN) / 4, 256, 0, stream>>>(nullptr, coords, mask, out);
    }
}

// Round 5
// 86.872 us; speedup vs baseline: 2.2438x; 1.1866x over previous
//
#include <hip/hip_runtime.h>
#include <math.h>

// Problem constants
#define NA   12            // atoms per residue
#define NL   256           // residues
#define NN   3072          // NL*NA atoms per batch
#define NB   2             // batches
#define ED   32            // embedding dim
#define KNB  30            // neighbours
#define BIGD 1000000.0f

// Flat output offsets (all stored as float32; int outputs stored as float values)
#define OFF_COORDS 0                       // 2*3072*3   = 18432
#define OFF_MASK   18432                   // 2*3072     = 6144
#define OFF_ENC    24576                   // 2*3072*32  = 196608
#define OFF_DIST   221184                  // 2*3072*30  = 184320
#define OFF_IDX    405504                  // 2*3072*30  = 184320

// ws layout: byte 512+: packed float4 coords {x,y,z,validmask}
#define WS_C4_BYTE_OFF 512
#define WS_NEEDED (WS_C4_BYTE_OFF + (size_t)NB * NN * 16)

// key packing: top 20 bits = float bits of SQUARED dist (positive -> uint order
// == float order; sqrt is monotone so d^2-selection == d-selection), low 12
// bits = atom index (0..3071). min(key) == lexicographic (dist, idx) min with
// smallest-index tie-break == jax top_k semantics.
#define KEYVAL 0xFFFFF000u
#define KEYIDX 0x00000FFFu
#define MASKED_D2 1e12f    // sqrt -> 1e6 == BIGD

static __device__ __forceinline__ unsigned umin32(unsigned a, unsigned b) {
    return a < b ? a : b;
}

// ---------------------------------------------------------------------------
// Kernel 1: fused stats + encode + atom_coords copy + atom_mask expand +
//           packed float4 {x,y,z,valid} for topk.
// Per-wave redundant mask-sum (256 ints) replaces a separate stats kernel.
// ---------------------------------------------------------------------------
__global__ __launch_bounds__(256) void prep_kernel(const float* __restrict__ coords,
                                                   const int* __restrict__ mask,
                                                   const float* __restrict__ emb,
                                                   const float* __restrict__ scale,
                                                   const float* __restrict__ shift,
                                                   float* __restrict__ out,
                                                   float4* __restrict__ c4pack) {
    int idx  = blockIdx.x * 256 + threadIdx.x;     // 0..196607, enc element
    int lane = threadIdx.x & 63;
    int b = idx / (NN * ED);                       // batch (block-uniform)

    // wave-level mask sum for batch b (int4 load: 64 lanes x 4 = 256 residues)
    const int4* m4 = (const int4*)(mask + b * NL);
    int4 mv = m4[lane];
    float S = (float)(mv.x + mv.y + mv.z + mv.w);
#pragma unroll
    for (int m = 1; m < 64; m <<= 1) S += __shfl_xor(S, m);

    // per-channel analytic graph-norm stats
    int c = idx & (ED - 1);
    float e[NA];
    float colsum = 0.f;
#pragma unroll
    for (int a = 0; a < NA; ++a) { e[a] = emb[a * ED + c]; colsum += e[a]; }
    float cnt  = fmaxf(12.0f * S, 1.0f);
    float mean = S * colsum / cnt;
    float acc  = 0.f;
#pragma unroll
    for (int a = 0; a < NA; ++a) { float dd = e[a] - mean; acc += dd * dd; }
    float var  = (S * acc + ((float)NN - 12.0f * S) * mean * mean) / cnt;
    float rstd = 1.0f / sqrtf(var + 1e-5f);

    // encode output
    int n  = (idx >> 5) % NN;
    int mi = mask[b * NL + n / NA];
    float v = 0.f;
    if (mi) {
        float en = emb[(n % NA) * ED + c];         // reload (avoids dynamic reg idx)
        v = (en - mean) * rstd * scale[c] + shift[c];
    }
    out[OFF_ENC + idx] = v;

    if (idx < NB * NN * 3) {
        out[OFF_COORDS + idx] = coords[idx];       // pure reshape
    }
    if (idx < NB * NN) {
        int bb = idx / NN, nn = idx - bb * NN;
        float m = (float)mask[bb * NL + nn / NA];
        out[OFF_MASK + idx] = m;
        if (c4pack) {
            float4 p;
            p.x = coords[idx * 3 + 0];
            p.y = coords[idx * 3 + 1];
            p.z = coords[idx * 3 + 2];
            p.w = m;
            c4pack[idx] = p;
        }
    }
}

// ---------------------------------------------------------------------------
// Kernel 2: per-row top-30. One wave per row (4 rows per 256-thread block).
// 48 packed d^2-keys per lane in real VGPRs (launch_bounds(256,2) lifts the
// register cap so nothing round-trips through AGPRs/scratch); 6 cached
// group-min keys; all compares are v_min_u32. Scalar-branched 8-element
// removal+rescan per extraction; 4-step DPP min ladder + readlane/s_min.
// ---------------------------------------------------------------------------

#define DPP_MIN_STEP(CTRL)                                                        \
    {                                                                             \
        int t_ = __builtin_amdgcn_update_dpp(v_, v_, (CTRL), 0xf, 0xf, false);    \
        v_ = (int)umin32((unsigned)v_, (unsigned)t_);                             \
    }

#define TREE8(A0,A1,A2,A3,A4,A5,A6,A7) \
    umin32(umin32(umin32((A0),(A1)), umin32((A2),(A3))), \
           umin32(umin32((A4),(A5)), umin32((A6),(A7))))

#define REMOVE_RESCAN(G)                                                          \
    {                                                                             \
        _Pragma("unroll")                                                         \
        for (int u = 0; u < 8; ++u) {                                             \
            const int t = (G) * 8 + u;                                            \
            k[t] = (k[t] == wkey) ? 0xFFFFFFFFu : k[t];                           \
        }                                                                         \
        gm[(G)] = TREE8(k[(G)*8+0],k[(G)*8+1],k[(G)*8+2],k[(G)*8+3],              \
                        k[(G)*8+4],k[(G)*8+5],k[(G)*8+6],k[(G)*8+7]);             \
    }

template <bool PACKED>
__global__ __launch_bounds__(256, 2) void topk_kernel(const float4* __restrict__ c4,
                                                      const float* __restrict__ coords,
                                                      const int* __restrict__ mask,
                                                      float* __restrict__ out) {
    int lane = threadIdx.x & 63;
    int row  = blockIdx.x * 4 + (threadIdx.x >> 6);   // 0..6143, one wave per row
    int b = (row >= NN) ? 1 : 0;
    int i = row - b * NN;

    // own row validity + query coords
    float qx, qy, qz, qw;
    if (PACKED) {
        float4 q4 = c4[b * NN + i];
        qx = q4.x; qy = q4.y; qz = q4.z; qw = q4.w;
    } else {
        const float* cb = coords + (size_t)b * NN * 3;
        qx = cb[i * 3 + 0]; qy = cb[i * 3 + 1]; qz = cb[i * 3 + 2];
        qw = (float)mask[b * NL + i / NA];
    }
    if (qw == 0.f) {                 // padded row: dist=BIG, idx=0
        if (lane < KNB) {
            out[OFF_DIST + (size_t)row * KNB + lane] = BIGD;
            out[OFF_IDX  + (size_t)row * KNB + lane] = 0.f;
        }
        return;
    }

    unsigned k[48];
    unsigned gm[6];

#pragma unroll
    for (int t = 0; t < 48; ++t) {
        int j = t * 64 + lane;
        float x, y, z, w;
        if (PACKED) {
            float4 v = c4[b * NN + j];
            x = v.x; y = v.y; z = v.z; w = v.w;
        } else {
            const float* cb = coords + (size_t)b * NN * 3;
            int r = (j * 43691) >> 19;          // j / 12 (magic)
            w = (float)mask[b * NL + r];
            x = cb[j * 3 + 0]; y = cb[j * 3 + 1]; z = cb[j * 3 + 2];
        }
        float dx = x - qx, dy = y - qy, dz = z - qz;
        float s = dx * dx + dy * dy + dz * dz + 1e-6f;   // squared dist (no sqrt!)
        s = (w != 0.f) ? s : MASKED_D2;
        k[t] = (__float_as_uint(s) & KEYVAL) | (unsigned)j;
    }
#pragma unroll
    for (int g = 0; g < 6; ++g)
        gm[g] = TREE8(k[g*8+0],k[g*8+1],k[g*8+2],k[g*8+3],
                      k[g*8+4],k[g*8+5],k[g*8+6],k[g*8+7]);

    unsigned cur = umin32(umin32(umin32(gm[0], gm[1]), umin32(gm[2], gm[3])),
                          umin32(gm[4], gm[5]));
    unsigned rkey = 0u;

    for (int it = 0; it < KNB; ++it) {
        // 4-step DPP min ladder -> each 16-lane row holds its row min in all
        // lanes; then 4 readlanes + scalar mins (SALU) give the global min.
        int v_ = (int)cur;
        DPP_MIN_STEP(0xB1)   // quad_perm [1,0,3,2]  (xor 1)
        DPP_MIN_STEP(0x4E)   // quad_perm [2,3,0,1]  (xor 2)
        DPP_MIN_STEP(0x141)  // row_half_mirror      (octet min)
        DPP_MIN_STEP(0x140)  // row_mirror           (row16 min)
        unsigned r0  = (unsigned)__builtin_amdgcn_readlane(v_, 0);
        unsigned r16 = (unsigned)__builtin_amdgcn_readlane(v_, 16);
        unsigned r32 = (unsigned)__builtin_amdgcn_readlane(v_, 32);
        unsigned r48 = (unsigned)__builtin_amdgcn_readlane(v_, 48);
        unsigned wkey = umin32(umin32(r0, r16), umin32(r32, r48));   // SGPR
        rkey = (lane == it) ? wkey : rkey;

        int wg = (int)((wkey & KEYIDX) >> 9);      // j>>6 = slot, slot>>3 = group
        switch (wg) {                               // scalar branch
            case 0: REMOVE_RESCAN(0); break;
            case 1: REMOVE_RESCAN(1); break;
            case 2: REMOVE_RESCAN(2); break;
            case 3: REMOVE_RESCAN(3); break;
            case 4: REMOVE_RESCAN(4); break;
            default: REMOVE_RESCAN(5); break;
        }
        cur = umin32(umin32(umin32(gm[0], gm[1]), umin32(gm[2], gm[3])),
                     umin32(gm[4], gm[5]));
    }

    if (lane < KNB) {
        float d2 = __uint_as_float(rkey & KEYVAL);
        out[OFF_DIST + (size_t)row * KNB + lane] = sqrtf(d2);
        out[OFF_IDX  + (size_t)row * KNB + lane] = (float)(rkey & KEYIDX);
    }
}

// ---------------------------------------------------------------------------
extern "C" void kernel_launch(void* const* d_in, const int* in_sizes, int n_in,
                              void* d_out, int out_size, void* d_ws, size_t ws_size,
                              hipStream_t stream) {
    const float* coords = (const float*)d_in[0];   // (2,256,12,3)
    const int*   mask   = (const int*)d_in[1];     // (2,256)
    const float* emb    = (const float*)d_in[2];   // (12,32)
    const float* scale  = (const float*)d_in[3];   // (32)
    const float* shift  = (const float*)d_in[4];   // (32)
    float* out = (float*)d_out;

    bool packed = (ws_size >= WS_NEEDED);
    float4* c4 = packed ? (float4*)((char*)d_ws + WS_C4_BYTE_OFF) : nullptr;

    prep_kernel<<<(NB * NN * ED) / 256, 256, 0, stream>>>(
        coords, mask, emb, scale, shift, out, c4);
    if (packed) {
        topk_kernel<true><<<(NB * NN) / 4, 256, 0, stream>>>(c4, coords, mask, out);
    } else {
        topk_kernel<false><<<(NB * NN) / 4, 256, 0, stream>>>(nullptr, coords, mask, out);
    }
}